// Round 1
// baseline (234.847 us; speedup 1.0000x reference)
//
#include <hip/hip_runtime.h>

#define N 192
#define N2 (N * N)
#define N3 (N * N * N)

static constexpr float INV2DX     = (float)N / 2.0f;   // 1/(2*DX), DX = 1/N
static constexpr float MU_REF_F   = 1.8e-5f;
static constexpr float CP_OVER_PR = 1005.0f / 0.72f;
static constexpr float TWO_THIRDS = 2.0f / 3.0f;

// Evaluate the direction-J flux column (tau_0J, tau_1J, tau_2J, F_J) at the
// face-neighbor point y = x + (D0,D1,D2), and accumulate sgn * column into the
// running divergence sums. All offsets are compile-time constants; the o*
// tables hold pre-wrapped, pre-multiplied periodic coordinates for offsets
// -2..+2 in each dimension, so every load is f[o0[a]+o1[b]+o2[c]].
template <int J, int D0, int D1, int D2>
__device__ __forceinline__ void accum_face(
    const float* __restrict__ u0, const float* __restrict__ u1,
    const float* __restrict__ u2, const float* __restrict__ Tp,
    const int* o0, const int* o1, const int* o2,
    float sgn, float& m0, float& m1, float& m2, float& en)
{
#define OFF(A, B, C) (o0[(A) + 2] + o1[(B) + 2] + o2[(C) + 2])
#define DD(f, b)                                                         \
    ((f[OFF(D0 + ((b) == 0), D1 + ((b) == 1), D2 + ((b) == 2))] -        \
      f[OFF(D0 - ((b) == 0), D1 - ((b) == 1), D2 - ((b) == 2))]) * INV2DX)

    const float* uJ = (J == 0) ? u0 : (J == 1) ? u1 : u2;

    // 7 distinct central derivatives at y (duplicates folded at compile time)
    float d0J = DD(u0, J);
    float d1J = DD(u1, J);
    float d2J = DD(u2, J);
    float dJ0 = (J == 0) ? d0J : DD(uJ, 0);
    float dJ1 = (J == 1) ? d1J : DD(uJ, 1);
    float dJ2 = (J == 2) ? d2J : DD(uJ, 2);
    float d00 = (J == 0) ? d0J : DD(u0, 0);
    float d11 = (J == 1) ? d1J : DD(u1, 1);
    float d22 = (J == 2) ? d2J : DD(u2, 2);

    float divu = d00 + d11 + d22;
    float Tc   = Tp[OFF(D0, D1, D2)];
    float mu   = MU_REF_F * __powf(Tc, 0.7f);   // T_dim/T_REF == T (nondim)
    float lam  = -TWO_THIRDS * mu * divu;

    float t0 = mu * (d0J + dJ0) + ((J == 0) ? lam : 0.0f);
    float t1 = mu * (d1J + dJ1) + ((J == 1) ? lam : 0.0f);
    float t2 = mu * (d2J + dJ2) + ((J == 2) ? lam : 0.0f);

    float dTJ = DD(Tp, J);
    float F   = mu * CP_OVER_PR * dTJ
              + t0 * u0[OFF(D0, D1, D2)]
              + t1 * u1[OFF(D0, D1, D2)]
              + t2 * u2[OFF(D0, D1, D2)];

    m0 += sgn * t0;
    m1 += sgn * t1;
    m2 += sgn * t2;
    en += sgn * F;
#undef OFF
#undef DD
}

__global__ __launch_bounds__(256)
void diffusion_rhs_kernel(const float* __restrict__ u,
                          const float* __restrict__ Tp,
                          float* __restrict__ out)
{
    const int i2 = blockIdx.x * 64 + threadIdx.x;  // contiguous (coalesced)
    const int i1 = blockIdx.y * 4 + threadIdx.y;
    const int i0 = blockIdx.z;

    // Pre-wrapped periodic coordinates for offsets -2..+2, pre-multiplied to
    // flat-index contributions. Wrap cost is per-thread, not per-load.
    int o0[5], o1[5], o2[5];
#pragma unroll
    for (int k = 0; k < 5; ++k) {
        int a = i0 + (k - 2); if (a < 0) a += N; if (a >= N) a -= N;
        int b = i1 + (k - 2); if (b < 0) b += N; if (b >= N) b -= N;
        int c = i2 + (k - 2); if (c < 0) c += N; if (c >= N) c -= N;
        o0[k] = a * N2;
        o1[k] = b * N;
        o2[k] = c;
    }

    const float* u0 = u;
    const float* u1 = u + N3;
    const float* u2 = u + 2 * N3;

    float m0 = 0.f, m1 = 0.f, m2 = 0.f, en = 0.f;
    accum_face<0,  1, 0, 0>(u0, u1, u2, Tp, o0, o1, o2, +1.f, m0, m1, m2, en);
    accum_face<0, -1, 0, 0>(u0, u1, u2, Tp, o0, o1, o2, -1.f, m0, m1, m2, en);
    accum_face<1,  0, 1, 0>(u0, u1, u2, Tp, o0, o1, o2, +1.f, m0, m1, m2, en);
    accum_face<1,  0,-1, 0>(u0, u1, u2, Tp, o0, o1, o2, -1.f, m0, m1, m2, en);
    accum_face<2,  0, 0, 1>(u0, u1, u2, Tp, o0, o1, o2, +1.f, m0, m1, m2, en);
    accum_face<2,  0, 0,-1>(u0, u1, u2, Tp, o0, o1, o2, -1.f, m0, m1, m2, en);

    const size_t idx = (size_t)o0[2] + o1[2] + o2[2];
    out[idx]                   = 0.0f;             // mass channel
    out[(size_t)1 * N3 + idx]  = m0 * INV2DX;
    out[(size_t)2 * N3 + idx]  = m1 * INV2DX;
    out[(size_t)3 * N3 + idx]  = m2 * INV2DX;
    out[(size_t)4 * N3 + idx]  = en * INV2DX;
}

extern "C" void kernel_launch(void* const* d_in, const int* in_sizes, int n_in,
                              void* d_out, int out_size, void* d_ws, size_t ws_size,
                              hipStream_t stream)
{
    const float* u  = (const float*)d_in[0];   // [3, N, N, N]
    const float* T  = (const float*)d_in[1];   // [N, N, N]
    float*       out = (float*)d_out;          // [5, N, N, N]

    dim3 block(64, 4, 1);
    dim3 grid(N / 64, N / 4, N);
    hipLaunchKernelGGL(diffusion_rhs_kernel, grid, block, 0, stream, u, T, out);
}

// Round 2
// 197.262 us; speedup vs baseline: 1.1905x; 1.1905x over previous
//
#include <hip/hip_runtime.h>

#define N  192
#define N2 (N * N)
#define N3 (N * N * N)

// Tile: axis2 (fastest) x TX, axis1 x TY, axis0 x TZ
#define TX 16
#define TY 8
#define TZ 4
#define RX (TX + 2)            // flux region incl. halo 1
#define RY (TY + 2)
#define RZ (TZ + 2)
#define RP (RX * RY * RZ)      // 18*10*6 = 1080 flux points / block
#define NT (TX * TY * TZ)      // 512 threads / block

#define S0 (RX * RY)           // LDS stride axis0
#define S1 RX                  // LDS stride axis1
#define S2 1                   // LDS stride axis2

static constexpr float INV2DX     = (float)N / 2.0f;   // 1/(2*DX), DX = 1/N
static constexpr float MU_REF_F   = 1.8e-5f;
static constexpr float CP_OVER_PR = 1005.0f / 0.72f;
static constexpr float TWO_THIRDS = 2.0f / 3.0f;

__device__ __forceinline__ int wrapN(int a) {  // valid for a in [-N, 2N)
    if (a < 0)  a += N;
    if (a >= N) a -= N;
    return a;
}

// LDS fields: 0:t00 1:t01 2:t02 3:t11 4:t12 5:t22 6:F0 7:F1 8:F2
__global__ __launch_bounds__(NT)
void diffusion_flux_lds_kernel(const float* __restrict__ u,
                               const float* __restrict__ Tp,
                               float* __restrict__ out)
{
    __shared__ float g[9 * RP];

    const int tx = threadIdx.x, ty = threadIdx.y, tz = threadIdx.z;
    const int bx = blockIdx.x * TX;   // axis2 origin
    const int by = blockIdx.y * TY;   // axis1 origin
    const int bz = blockIdx.z * TZ;   // axis0 origin
    const int tid = (tz * TY + ty) * TX + tx;

    const float* __restrict__ u0 = u;
    const float* __restrict__ u1 = u + N3;
    const float* __restrict__ u2 = u + 2 * N3;

    // ---- Phase 1: flux columns at every region point (tile + halo 1) ----
    for (int p = tid; p < RP; p += NT) {
        const int lx = p % RX;
        const int tq = p / RX;
        const int ly = tq % RY;
        const int lz = tq / RY;

        const int xr = bx + lx - 1;          // raw coords, in [-1, N]
        const int yr = by + ly - 1;
        const int zr = bz + lz - 1;

        const int xw = wrapN(xr), xm = wrapN(xr - 1), xp = wrapN(xr + 1);
        const int yw = wrapN(yr), ym = wrapN(yr - 1), yp = wrapN(yr + 1);
        const int zw = wrapN(zr), zm = wrapN(zr - 1), zp = wrapN(zr + 1);

        const int rowc = zw * N2 + yw * N;
        const int c    = rowc + xw;
        const int cxm  = rowc + xm,          cxp = rowc + xp;
        const int cym  = zw * N2 + ym * N + xw, cyp = zw * N2 + yp * N + xw;
        const int czm  = zm * N2 + yw * N + xw, czp = zp * N2 + yw * N + xw;

        // 9 velocity gradients d[i][a] = d u_i / d x_a  (axis0=z-slow .. axis2=x-fast)
        const float d00 = (u0[czp] - u0[czm]) * INV2DX;
        const float d01 = (u0[cyp] - u0[cym]) * INV2DX;
        const float d02 = (u0[cxp] - u0[cxm]) * INV2DX;
        const float d10 = (u1[czp] - u1[czm]) * INV2DX;
        const float d11 = (u1[cyp] - u1[cym]) * INV2DX;
        const float d12 = (u1[cxp] - u1[cxm]) * INV2DX;
        const float d20 = (u2[czp] - u2[czm]) * INV2DX;
        const float d21 = (u2[cyp] - u2[cym]) * INV2DX;
        const float d22 = (u2[cxp] - u2[cxm]) * INV2DX;

        const float dT0 = (Tp[czp] - Tp[czm]) * INV2DX;
        const float dT1 = (Tp[cyp] - Tp[cym]) * INV2DX;
        const float dT2 = (Tp[cxp] - Tp[cxm]) * INV2DX;

        const float Tc  = Tp[c];
        const float v0  = u0[c], v1 = u1[c], v2 = u2[c];

        const float mu   = MU_REF_F * __powf(Tc, 0.7f);
        const float divu = d00 + d11 + d22;
        const float lam  = -TWO_THIRDS * mu * divu;

        const float t00 = 2.0f * mu * d00 + lam;
        const float t11 = 2.0f * mu * d11 + lam;
        const float t22 = 2.0f * mu * d22 + lam;
        const float t01 = mu * (d01 + d10);
        const float t02 = mu * (d02 + d20);
        const float t12 = mu * (d12 + d21);

        const float kc = mu * CP_OVER_PR;
        const float F0 = kc * dT0 + t00 * v0 + t01 * v1 + t02 * v2;
        const float F1 = kc * dT1 + t01 * v0 + t11 * v1 + t12 * v2;
        const float F2 = kc * dT2 + t02 * v0 + t12 * v1 + t22 * v2;

        g[0 * RP + p] = t00;
        g[1 * RP + p] = t01;
        g[2 * RP + p] = t02;
        g[3 * RP + p] = t11;
        g[4 * RP + p] = t12;
        g[5 * RP + p] = t22;
        g[6 * RP + p] = F0;
        g[7 * RP + p] = F1;
        g[8 * RP + p] = F2;
    }

    __syncthreads();

    // ---- Phase 2: divergence from LDS, write 5 output channels ----
    const int lin = (tz + 1) * S0 + (ty + 1) * S1 + (tx + 1);
#define G(f, d) g[(f) * RP + lin + (d)]
    const float m0 = (G(0, S0) - G(0, -S0)) + (G(1, S1) - G(1, -S1)) + (G(2, S2) - G(2, -S2));
    const float m1 = (G(1, S0) - G(1, -S0)) + (G(3, S1) - G(3, -S1)) + (G(4, S2) - G(4, -S2));
    const float m2 = (G(2, S0) - G(2, -S0)) + (G(4, S1) - G(4, -S1)) + (G(5, S2) - G(5, -S2));
    const float en = (G(6, S0) - G(6, -S0)) + (G(7, S1) - G(7, -S1)) + (G(8, S2) - G(8, -S2));
#undef G

    const int idx = (bz + tz) * N2 + (by + ty) * N + (bx + tx);
    out[idx]              = 0.0f;          // mass channel
    out[1 * N3 + idx]     = m0 * INV2DX;
    out[2 * N3 + idx]     = m1 * INV2DX;
    out[3 * N3 + idx]     = m2 * INV2DX;
    out[4 * N3 + idx]     = en * INV2DX;
}

extern "C" void kernel_launch(void* const* d_in, const int* in_sizes, int n_in,
                              void* d_out, int out_size, void* d_ws, size_t ws_size,
                              hipStream_t stream)
{
    const float* u   = (const float*)d_in[0];   // [3, N, N, N]
    const float* T   = (const float*)d_in[1];   // [N, N, N]
    float*       out = (float*)d_out;           // [5, N, N, N]

    dim3 block(TX, TY, TZ);                     // 512 threads
    dim3 grid(N / TX, N / TY, N / TZ);          // 12 x 24 x 48
    hipLaunchKernelGGL(diffusion_flux_lds_kernel, grid, block, 0, stream, u, T, out);
}

// Round 3
// 145.342 us; speedup vs baseline: 1.6158x; 1.3572x over previous
//
#include <hip/hip_runtime.h>

#define N  192
#define N2 (N * N)
#define N3 (N * N * N)

// Block: 32x8 (x,y) tile marching ZC planes in z (axis0).
#define TX 32
#define TY 8
#define NT (TX * TY)          // 256 threads
#define ZC 24                 // z-planes per block -> grid (6,24,8) = 1152 blocks
#define UX (TX + 4)           // u/T staged with halo +-2 in x,y
#define UY (TY + 4)
#define UP (UX * UY)          // 432
#define FX (TX + 2)           // flux plane with halo +-1
#define FY (TY + 2)
#define FP (FX * FY)          // 340

static constexpr float INV2DX     = (float)N / 2.0f;   // 1/(2*DX), DX = 1/N
static constexpr float MU_REF_F   = 1.8e-5f;
static constexpr float CP_OVER_PR = 1005.0f / 0.72f;
static constexpr float TWO_THIRDS = 2.0f / 3.0f;

__device__ __forceinline__ int wrapN(int a) {  // valid for a in [-N, 2N)
    if (a < 0)  a += N;
    if (a >= N) a -= N;
    return a;
}

struct Flux { float t00, t01, t02, t11, t12, t22, F0, F1, F2; };

// Flux column at u-region LDS index c, from 3 staged planes (k-1, k, k+1).
// Each plane is float[4][UP], fields 0..2 = u0..u2, 3 = T.
__device__ __forceinline__ Flux flux_eval(const float* __restrict__ uM,
                                          const float* __restrict__ uC,
                                          const float* __restrict__ uP,
                                          int c)
{
    const float d00 = (uP[0 * UP + c]      - uM[0 * UP + c])      * INV2DX;
    const float d01 = (uC[0 * UP + c + UX] - uC[0 * UP + c - UX]) * INV2DX;
    const float d02 = (uC[0 * UP + c + 1]  - uC[0 * UP + c - 1])  * INV2DX;
    const float d10 = (uP[1 * UP + c]      - uM[1 * UP + c])      * INV2DX;
    const float d11 = (uC[1 * UP + c + UX] - uC[1 * UP + c - UX]) * INV2DX;
    const float d12 = (uC[1 * UP + c + 1]  - uC[1 * UP + c - 1])  * INV2DX;
    const float d20 = (uP[2 * UP + c]      - uM[2 * UP + c])      * INV2DX;
    const float d21 = (uC[2 * UP + c + UX] - uC[2 * UP + c - UX]) * INV2DX;
    const float d22 = (uC[2 * UP + c + 1]  - uC[2 * UP + c - 1])  * INV2DX;

    const float dT0 = (uP[3 * UP + c]      - uM[3 * UP + c])      * INV2DX;
    const float dT1 = (uC[3 * UP + c + UX] - uC[3 * UP + c - UX]) * INV2DX;
    const float dT2 = (uC[3 * UP + c + 1]  - uC[3 * UP + c - 1])  * INV2DX;

    const float Tc = uC[3 * UP + c];
    const float v0 = uC[0 * UP + c], v1 = uC[1 * UP + c], v2 = uC[2 * UP + c];

    const float mu   = MU_REF_F * __powf(Tc, 0.7f);
    const float divu = d00 + d11 + d22;
    const float lam  = -TWO_THIRDS * mu * divu;

    Flux f;
    f.t00 = 2.0f * mu * d00 + lam;
    f.t11 = 2.0f * mu * d11 + lam;
    f.t22 = 2.0f * mu * d22 + lam;
    f.t01 = mu * (d01 + d10);
    f.t02 = mu * (d02 + d20);
    f.t12 = mu * (d12 + d21);
    const float kc = mu * CP_OVER_PR;
    f.F0 = kc * dT0 + f.t00 * v0 + f.t01 * v1 + f.t02 * v2;
    f.F1 = kc * dT1 + f.t01 * v0 + f.t11 * v1 + f.t12 * v2;
    f.F2 = kc * dT2 + f.t02 * v0 + f.t12 * v1 + f.t22 * v2;
    return f;
}

__device__ __forceinline__ void load_plane(float* __restrict__ dst,  // float[4][UP]
                                           const float* __restrict__ u0,
                                           const float* __restrict__ u1,
                                           const float* __restrict__ u2,
                                           const float* __restrict__ Tp,
                                           int zw, int bx, int by, int tid)
{
    const int base = zw * N2;
    for (int q = tid; q < UP; q += NT) {
        const int ux = q % UX;
        const int uy = q / UX;
        const int xg = wrapN(bx + ux - 2);
        const int yg = wrapN(by + uy - 2);
        const int g  = base + yg * N + xg;
        dst[0 * UP + q] = u0[g];
        dst[1 * UP + q] = u1[g];
        dst[2 * UP + q] = u2[g];
        dst[3 * UP + q] = Tp[g];
    }
}

// sf xy-divergence fields: 0:t01 1:t02 2:t11 3:t12 4:t22 5:F1 6:F2
#define SF_STORE(buf, fi, f)                 \
    do {                                     \
        sf[buf][0][fi] = (f).t01;            \
        sf[buf][1][fi] = (f).t02;            \
        sf[buf][2][fi] = (f).t11;            \
        sf[buf][3][fi] = (f).t12;            \
        sf[buf][4][fi] = (f).t22;            \
        sf[buf][5][fi] = (f).F1;             \
        sf[buf][6][fi] = (f).F2;             \
    } while (0)

__global__ __launch_bounds__(NT)
void diffusion_zmarch_kernel(const float* __restrict__ u,
                             const float* __restrict__ Tp,
                             float* __restrict__ out)
{
    __shared__ float su[3][4 * UP];   // rolling u/T planes      (20.25 KB)
    __shared__ float sf[2][7][FP];    // double-buffered fluxes  (19.04 KB)

    const int tx  = threadIdx.x, ty = threadIdx.y;
    const int tid = ty * TX + tx;
    const int bx  = blockIdx.x * TX;
    const int by  = blockIdx.y * TY;
    const int z0  = blockIdx.z * ZC;

    const float* __restrict__ u0 = u;
    const float* __restrict__ u1 = u + N3;
    const float* __restrict__ u2 = u + 2 * N3;

    // u-region index of this thread's interior point; flux-plane index
    const int cu = (ty + 2) * UX + (tx + 2);
    const int fi = (ty + 1) * FX + (tx + 1);

    // halo flux site for tid < 80 (corners excluded — never read)
    int hfx = -1, hfy = -1;
    if (tid < TX)                { hfy = 0;      hfx = 1 + tid; }
    else if (tid < 2 * TX)       { hfy = FY - 1; hfx = 1 + tid - TX; }
    else if (tid < 2 * TX + TY)  { hfx = 0;      hfy = 1 + tid - 2 * TX; }
    else if (tid < 2 * (TX + TY)){ hfx = FX - 1; hfy = 1 + tid - 2 * TX - TY; }
    const int hcu = (hfy + 1) * UX + (hfx + 1);
    const int hfi = hfy * FX + hfx;

    // ---- prologue ----
    load_plane(su[2], u0, u1, u2, Tp, wrapN(z0 - 2), bx, by, tid);
    load_plane(su[0], u0, u1, u2, Tp, wrapN(z0 - 1), bx, by, tid);
    load_plane(su[1], u0, u1, u2, Tp, z0,            bx, by, tid);
    __syncthreads();

    // flux(z0-1): interior z-fields only
    float t00m, t01m, t02m, F0m;
    {
        Flux f = flux_eval(su[2], su[0], su[1], cu);
        t00m = f.t00; t01m = f.t01; t02m = f.t02; F0m = f.F0;
    }
    __syncthreads();                               // before overwriting slot 2

    load_plane(su[2], u0, u1, u2, Tp, z0 + 1, bx, by, tid);
    __syncthreads();

    // flux(z0): full plane -> c-regs + sf[0]
    float t00c, t01c, t02c, F0c;
    {
        Flux f = flux_eval(su[0], su[1], su[2], cu);
        t00c = f.t00; t01c = f.t01; t02c = f.t02; F0c = f.F0;
        SF_STORE(0, fi, f);
        if (hfx >= 0) {
            Flux h = flux_eval(su[0], su[1], su[2], hcu);
            SF_STORE(0, hfi, h);
        }
    }
    __syncthreads();                               // before loop's first load (slot 0)

    int sA = 1, sB = 2, sC = 0;                    // u slots: z, z+1, (incoming z+2)
    int cur = 1;                                   // sf write buffer this iteration

    const int obase = by * N + bx + ty * N + tx;

    // ---- main loop: one output plane per iteration ----
    for (int z = z0; z < z0 + ZC; ++z) {
        load_plane(su[sC], u0, u1, u2, Tp, wrapN(z + 2), bx, by, tid);
        __syncthreads();                           // u(z+2) ready

        // flux(z+1) -> p-regs + sf[cur]
        Flux fp = flux_eval(su[sA], su[sB], su[sC], cu);
        SF_STORE(cur, fi, fp);
        if (hfx >= 0) {
            Flux h = flux_eval(su[sA], su[sB], su[sC], hcu);
            SF_STORE(cur, hfi, h);
        }

        // output plane z: z-derivs from regs, xy-derivs from sf[prev]
        const int prev = cur ^ 1;
        const float* __restrict__ s0 = sf[prev][0];
        const float* __restrict__ s1 = sf[prev][1];
        const float* __restrict__ s2 = sf[prev][2];
        const float* __restrict__ s3 = sf[prev][3];
        const float* __restrict__ s4 = sf[prev][4];
        const float* __restrict__ s5 = sf[prev][5];
        const float* __restrict__ s6 = sf[prev][6];

        const float m0 = (fp.t00 - t00m) + (s0[fi + FX] - s0[fi - FX]) + (s1[fi + 1] - s1[fi - 1]);
        const float m1 = (fp.t01 - t01m) + (s2[fi + FX] - s2[fi - FX]) + (s3[fi + 1] - s3[fi - 1]);
        const float m2 = (fp.t02 - t02m) + (s3[fi + FX] - s3[fi - FX]) + (s4[fi + 1] - s4[fi - 1]);
        const float en = (fp.F0  - F0m)  + (s5[fi + FX] - s5[fi - FX]) + (s6[fi + 1] - s6[fi - 1]);

        const int idx = z * N2 + obase;
        out[idx]          = 0.0f;
        out[1 * N3 + idx] = m0 * INV2DX;
        out[2 * N3 + idx] = m1 * INV2DX;
        out[3 * N3 + idx] = m2 * INV2DX;
        out[4 * N3 + idx] = en * INV2DX;

        __syncthreads();                           // su[sA] reads done before next load

        // rotate pipeline state (compile-time-indexed shift registers)
        t00m = t00c; t01m = t01c; t02m = t02c; F0m = F0c;
        t00c = fp.t00; t01c = fp.t01; t02c = fp.t02; F0c = fp.F0;
        const int t = sA; sA = sB; sB = sC; sC = t;
        cur ^= 1;
    }
}

extern "C" void kernel_launch(void* const* d_in, const int* in_sizes, int n_in,
                              void* d_out, int out_size, void* d_ws, size_t ws_size,
                              hipStream_t stream)
{
    const float* u   = (const float*)d_in[0];   // [3, N, N, N]
    const float* T   = (const float*)d_in[1];   // [N, N, N]
    float*       out = (float*)d_out;           // [5, N, N, N]

    dim3 block(TX, TY, 1);                      // 256 threads
    dim3 grid(N / TX, N / TY, N / ZC);          // 6 x 24 x 8 = 1152 blocks
    hipLaunchKernelGGL(diffusion_zmarch_kernel, grid, block, 0, stream, u, T, out);
}

// Round 4
// 106.246 us; speedup vs baseline: 2.2104x; 1.3680x over previous
//
#include <hip/hip_runtime.h>

#define N  192
#define N2 (N * N)
#define N3 (N * N * N)

// Block: 32x8 (x,y) tile marching ZC planes in z (axis0).
#define TX 32
#define TY 8
#define NT 256
#define ZC 12
#define GX (N / TX)           // 6
#define GY (N / TY)           // 24
#define GZ (N / ZC)           // 16
#define NBLK (GX * GY * GZ)   // 2304 (divisible by 8 XCDs)
#define UX (TX + 4)           // 36  (u/T halo +-2)
#define UY (TY + 4)           // 12
#define UP (UX * UY)          // 432
#define FX (TX + 2)           // 34  (flux halo +-1)
#define FY (TY + 2)           // 10
#define FP (FX * FY)          // 340

static constexpr float INV2DX     = (float)N / 2.0f;
static constexpr float MU_REF_F   = 1.8e-5f;
static constexpr float CP_OVER_PR = 1005.0f / 0.72f;
static constexpr float TWO_THIRDS = 2.0f / 3.0f;

__device__ __forceinline__ int wrapN(int a) {  // valid for a in [-N, 2N)
    if (a < 0)  a += N;
    if (a >= N) a -= N;
    return a;
}

struct Flux { float t00, t01, t02, t11, t12, t22, F0, F1, F2; };

// u planes packed float4 per site: {u0, u1, u2, T}. 7x ds_read_b128.
__device__ __forceinline__ Flux flux_eval(const float4* __restrict__ uM,
                                          const float4* __restrict__ uC,
                                          const float4* __restrict__ uP,
                                          int c)
{
    const float4 cc = uC[c];
    const float4 xp = uC[c + 1],  xm = uC[c - 1];
    const float4 yp = uC[c + UX], ym = uC[c - UX];
    const float4 zp = uP[c],      zm = uM[c];

    const float d00 = (zp.x - zm.x) * INV2DX;
    const float d01 = (yp.x - ym.x) * INV2DX;
    const float d02 = (xp.x - xm.x) * INV2DX;
    const float d10 = (zp.y - zm.y) * INV2DX;
    const float d11 = (yp.y - ym.y) * INV2DX;
    const float d12 = (xp.y - xm.y) * INV2DX;
    const float d20 = (zp.z - zm.z) * INV2DX;
    const float d21 = (yp.z - ym.z) * INV2DX;
    const float d22 = (xp.z - xm.z) * INV2DX;
    const float dT0 = (zp.w - zm.w) * INV2DX;
    const float dT1 = (yp.w - ym.w) * INV2DX;
    const float dT2 = (xp.w - xm.w) * INV2DX;

    const float mu   = MU_REF_F * __powf(cc.w, 0.7f);
    const float divu = d00 + d11 + d22;
    const float lam  = -TWO_THIRDS * mu * divu;

    Flux f;
    f.t00 = 2.0f * mu * d00 + lam;
    f.t11 = 2.0f * mu * d11 + lam;
    f.t22 = 2.0f * mu * d22 + lam;
    f.t01 = mu * (d01 + d10);
    f.t02 = mu * (d02 + d20);
    f.t12 = mu * (d12 + d21);
    const float kc = mu * CP_OVER_PR;
    f.F0 = kc * dT0 + f.t00 * cc.x + f.t01 * cc.y + f.t02 * cc.z;
    f.F1 = kc * dT1 + f.t01 * cc.x + f.t11 * cc.y + f.t12 * cc.z;
    f.F2 = kc * dT2 + f.t02 * cc.x + f.t12 * cc.y + f.t22 * cc.z;
    return f;
}

__device__ __forceinline__ void sf_store(float4* __restrict__ sA, float4* __restrict__ sB,
                                         int fi, const Flux& f)
{
    sA[fi] = make_float4(f.t01, f.t02, f.t11, f.t12);
    sB[fi] = make_float4(f.t22, f.F1,  f.F2,  0.0f);
}

__global__ __launch_bounds__(NT)
void diffusion_zmarch_kernel(const float* __restrict__ u,
                             const float* __restrict__ Tp,
                             float* __restrict__ out)
{
    __shared__ float4 su4[4][UP];     // rolling packed u/T planes (27.0 KB)
    __shared__ float4 sfA[2][FP];     // flux xy-fields {t01,t02,t11,t12} (10.6 KB)
    __shared__ float4 sfB[2][FP];     // flux xy-fields {t22,F1,F2,-}     (10.6 KB)

    // ---- bijective XCD swizzle on the flat block id (NBLK % 8 == 0) ----
    const int id  = (int)blockIdx.x;
    const int nid = (id & 7) * (NBLK / 8) + (id >> 3);
    const int bzB = nid / (GX * GY);
    const int rem = nid % (GX * GY);
    const int bx  = (rem % GX) * TX;
    const int by  = (rem / GX) * TY;
    const int z0  = bzB * ZC;

    const int tx  = threadIdx.x & (TX - 1);
    const int ty  = threadIdx.x >> 5;
    const int tid = (int)threadIdx.x;

    const float* __restrict__ u0 = u;
    const float* __restrict__ u1 = u + N3;
    const float* __restrict__ u2 = u + 2 * N3;

    const int cu = (ty + 2) * UX + (tx + 2);   // interior u-site
    const int fi = (ty + 1) * FX + (tx + 1);   // interior flux-site

    // halo flux site for tid < 80 (corners excluded — never read)
    int hfx = -1, hfy = -1;
    if (tid < TX)                 { hfy = 0;      hfx = 1 + tid; }
    else if (tid < 2 * TX)        { hfy = FY - 1; hfx = 1 + tid - TX; }
    else if (tid < 2 * TX + TY)   { hfx = 0;      hfy = 1 + tid - 2 * TX; }
    else if (tid < 2 * (TX + TY)) { hfx = FX - 1; hfy = 1 + tid - 2 * TX - TY; }
    const int hcu = (hfy + 1) * UX + (hfx + 1);
    const int hfi = hfy * FX + hfx;

    // staging sites for this thread (loop-invariant global row offsets)
    const int  q0   = tid;
    const int  q1   = tid + NT;
    const bool has2 = (q1 < UP);
    int ro0, ro1 = 0;
    {
        const int ux = q0 % UX, uy = q0 / UX;
        ro0 = wrapN(by + uy - 2) * N + wrapN(bx + ux - 2);
    }
    if (has2) {
        const int ux = q1 % UX, uy = q1 / UX;
        ro1 = wrapN(by + uy - 2) * N + wrapN(bx + ux - 2);
    }

#define STAGE_DIRECT(slot, zw)                                              \
    do {                                                                    \
        const int base_ = (zw) * N2;                                        \
        {  const int g_ = base_ + ro0;                                      \
           su4[slot][q0] = make_float4(u0[g_], u1[g_], u2[g_], Tp[g_]); }   \
        if (has2) {                                                         \
           const int g_ = base_ + ro1;                                      \
           su4[slot][q1] = make_float4(u0[g_], u1[g_], u2[g_], Tp[g_]); }   \
    } while (0)

    // ---- prologue: planes z0-2 .. z0+1 ----
    STAGE_DIRECT(0, wrapN(z0 - 2));
    STAGE_DIRECT(1, wrapN(z0 - 1));
    STAGE_DIRECT(2, z0);
    STAGE_DIRECT(3, z0 + 1);
    __syncthreads();

    float t00m, t01m, t02m, F0m;      // flux(z-1) z-fields
    float t00c, t01c, t02c, F0c;      // flux(z)   z-fields
    {
        const Flux fM = flux_eval(su4[0], su4[1], su4[2], cu);
        t00m = fM.t00; t01m = fM.t01; t02m = fM.t02; F0m = fM.F0;
        const Flux fC = flux_eval(su4[1], su4[2], su4[3], cu);
        t00c = fC.t00; t01c = fC.t01; t02c = fC.t02; F0c = fC.F0;
        sf_store(sfA[0], sfB[0], fi, fC);
        if (hfx >= 0) {
            const Flux h = flux_eval(su4[1], su4[2], su4[3], hcu);
            sf_store(sfA[0], sfB[0], hfi, h);
        }
    }
    __syncthreads();                   // slot0 reads done, sf[0] visible
    STAGE_DIRECT(0, z0 + 2);
    __syncthreads();

    float4 *pM = su4[2], *pC = su4[3], *pP = su4[0], *pW = su4[1];
    int cur = 1;
    const int obase = (by + ty) * N + bx + tx;

    // ---- main loop: one output plane per iteration, ONE barrier ----
    for (int z = z0; z < z0 + ZC; ++z) {
        // 1) issue next plane's global loads early (consumed next iteration)
        const bool pref = (z <= z0 + ZC - 2);
        float4 r0, r1;
        if (pref) {
            int zw = z + 3; if (zw >= N) zw -= N;
            const int base_ = zw * N2;
            { const int g_ = base_ + ro0;
              r0 = make_float4(u0[g_], u1[g_], u2[g_], Tp[g_]); }
            if (has2) {
              const int g_ = base_ + ro1;
              r1 = make_float4(u0[g_], u1[g_], u2[g_], Tp[g_]); }
        }

        // 2) flux(z+1) from LDS planes z..z+2 (loads still in flight)
        const Flux fp_ = flux_eval(pM, pC, pP, cu);
        Flux h;
        if (hfx >= 0) h = flux_eval(pM, pC, pP, hcu);

        // 3) output plane z: z-derivs from regs, xy-derivs from sf[prev]
        const float4* __restrict__ sA = sfA[cur ^ 1];
        const float4* __restrict__ sB = sfB[cur ^ 1];
        const float4 ayp = sA[fi + FX], aym = sA[fi - FX];
        const float4 axp = sA[fi + 1],  axm = sA[fi - 1];
        const float4 byp = sB[fi + FX], bym = sB[fi - FX];
        const float4 bxp = sB[fi + 1],  bxm = sB[fi - 1];

        const float m0 = (fp_.t00 - t00m) + (ayp.x - aym.x) + (axp.y - axm.y);
        const float m1 = (fp_.t01 - t01m) + (ayp.z - aym.z) + (axp.w - axm.w);
        const float m2 = (fp_.t02 - t02m) + (ayp.w - aym.w) + (bxp.x - bxm.x);
        const float en = (fp_.F0  - F0m)  + (byp.y - bym.y) + (bxp.z - bxm.z);

        const int idx = z * N2 + obase;
        out[idx]          = 0.0f;
        out[1 * N3 + idx] = m0 * INV2DX;
        out[2 * N3 + idx] = m1 * INV2DX;
        out[3 * N3 + idx] = m2 * INV2DX;
        out[4 * N3 + idx] = en * INV2DX;

        // 4) deferred LDS writes: next u plane + this flux plane
        if (pref) { pW[q0] = r0; if (has2) pW[q1] = r1; }
        sf_store(sfA[cur], sfB[cur], fi, fp_);
        if (hfx >= 0) sf_store(sfA[cur], sfB[cur], hfi, h);

        __syncthreads();

        // 5) rotate pipeline state
        t00m = t00c; t01m = t01c; t02m = t02c; F0m = F0c;
        t00c = fp_.t00; t01c = fp_.t01; t02c = fp_.t02; F0c = fp_.F0;
        float4* t = pM; pM = pC; pC = pP; pP = pW; pW = t;
        cur ^= 1;
    }
#undef STAGE_DIRECT
}

extern "C" void kernel_launch(void* const* d_in, const int* in_sizes, int n_in,
                              void* d_out, int out_size, void* d_ws, size_t ws_size,
                              hipStream_t stream)
{
    const float* u   = (const float*)d_in[0];   // [3, N, N, N]
    const float* T   = (const float*)d_in[1];   // [N, N, N]
    float*       out = (float*)d_out;           // [5, N, N, N]

    hipLaunchKernelGGL(diffusion_zmarch_kernel, dim3(NBLK), dim3(NT), 0, stream,
                       u, T, out);
}